// Round 4
// baseline (1317.723 us; speedup 1.0000x reference)
//
#include <hip/hip_runtime.h>
#include <cstdint>
#include <cstddef>

#define T_DIM 4096
#define B_DIM 32
#define D_DIM 512
#define H_DIM 256
#define G_DIM 1024  // 4*H
#define HSTR 264    // padded H-row stride in f16 elems (2-way LDS aliasing = free)
#define XSTR 1036   // padded xw-row stride in f16 elems (2072 B)
#define NBUCK 64    // LPT sort buckets (lengths >= NBUCK share the top bucket)

typedef _Float16 h8 __attribute__((ext_vector_type(8)));
typedef float f4 __attribute__((ext_vector_type(4)));

// ---------------------------------------------------------------------------
// Kernel A: per-batch segment extraction (atomic-free).
// ---------------------------------------------------------------------------
__global__ void seg_build_kernel(const int* __restrict__ reset,
                                 unsigned* __restrict__ starts,
                                 unsigned* __restrict__ segcnt) {
  __shared__ unsigned cnts[256];
  __shared__ unsigned offs[256];
  const int b = blockIdx.x;
  const int tid = threadIdx.x;
  const int t0 = tid * 16;
  unsigned c = 0;
  for (int e = 0; e < 16; ++e) {
    int t = t0 + e;
    bool pred = (t == 0) || (reset[t * B_DIM + b] != 0);
    c += pred ? 1u : 0u;
  }
  cnts[tid] = c;
  __syncthreads();
  if (tid == 0) {
    unsigned run = 0;
    for (int i = 0; i < 256; ++i) { unsigned v = cnts[i]; offs[i] = run; run += v; }
    segcnt[b] = run;
  }
  __syncthreads();
  unsigned o = (unsigned)b * 4096u + offs[tid];
  for (int e = 0; e < 16; ++e) {
    int t = t0 + e;
    bool pred = (t == 0) || (reset[t * B_DIM + b] != 0);
    if (pred) { starts[o++] = (unsigned)t; }
  }
}

// ---------------------------------------------------------------------------
// Kernel A2: flatten per-batch segment lists into one UNSORTED queue (flat2).
// flat2[i] = (t0 | b<<16, t1). meta[0]=pull counter (init 0), meta[1]=nseg.
// ---------------------------------------------------------------------------
__global__ void seg_flat_kernel(const unsigned* __restrict__ starts,
                                const unsigned* __restrict__ segcnt,
                                uint2* __restrict__ flat2,
                                unsigned* __restrict__ meta) {
  __shared__ unsigned offs;
  const int b = blockIdx.x;
  const int tid = threadIdx.x;
  if (tid == 0) {
    unsigned o = 0;
    for (int i = 0; i < b; ++i) o += segcnt[i];
    offs = o;
    if (b == 31) meta[1] = o + segcnt[31];
    if (b == 0) meta[0] = 0u;
  }
  __syncthreads();
  const unsigned cnt = segcnt[b];
  const unsigned off = offs;
  for (unsigned s = tid; s < cnt; s += 256) {
    unsigned t0 = starts[b * 4096u + s];
    unsigned t1 = (s + 1 < cnt) ? starts[b * 4096u + s + 1] : 4096u;
    flat2[off + s] = make_uint2(t0 | ((unsigned)b << 16), t1);
  }
}

// ---------------------------------------------------------------------------
// Kernel A3: LPT counting sort, single block, wave-aggregated atomics.
// ---------------------------------------------------------------------------
__global__ void seg_sort_kernel(const uint2* __restrict__ flat2,
                                uint2* __restrict__ flat,
                                const unsigned* __restrict__ meta) {
  __shared__ unsigned lh[NBUCK];
  __shared__ unsigned cur[NBUCK];
  const unsigned nseg = meta[1];
  const int tid = threadIdx.x;
  const int lane = tid & 63;
  if (tid < NBUCK) lh[tid] = 0u;
  __syncthreads();
  // phase 1: histogram (match-any aggregation)
  for (unsigned base = 0; base < nseg; base += 1024) {
    unsigned i = base + tid;
    bool act = i < nseg;
    unsigned bk = 0u;
    if (act) {
      uint2 e = flat2[i];
      bk = min(e.y - (e.x & 0xFFFFu), (unsigned)NBUCK) - 1u;
    }
    unsigned long long rem = __ballot(act);
    while (rem) {
      int ld = (int)__ffsll((unsigned long long)rem) - 1;
      unsigned lbk = __shfl(bk, ld);
      unsigned long long meq = __ballot(act && bk == lbk);
      if (lane == ld) atomicAdd(&lh[lbk], (unsigned)__popcll(meq));
      rem &= ~meq;
    }
  }
  __syncthreads();
  if (tid == 0) {
    unsigned run = 0;
    for (int k = NBUCK - 1; k >= 0; --k) { cur[k] = run; run += lh[k]; }
  }
  __syncthreads();
  // phase 2: scatter longest-first
  for (unsigned base = 0; base < nseg; base += 1024) {
    unsigned i = base + tid;
    bool act = i < nseg;
    uint2 e = make_uint2(0u, 0u);
    unsigned bk = 0u;
    if (act) {
      e = flat2[i];
      bk = min(e.y - (e.x & 0xFFFFu), (unsigned)NBUCK) - 1u;
    }
    unsigned long long rem = __ballot(act);
    unsigned pos = 0u;
    while (rem) {
      int ld = (int)__ffsll((unsigned long long)rem) - 1;
      unsigned lbk = __shfl(bk, ld);
      unsigned long long meq = __ballot(act && bk == lbk);
      unsigned bs = 0u;
      if (lane == ld) bs = atomicAdd(&cur[lbk], (unsigned)__popcll(meq));
      bs = __shfl(bs, ld);
      if (act && bk == lbk)
        pos = bs + (unsigned)__popcll(meq & ((1ull << lane) - 1ull));
      rem &= ~meq;
    }
    if (act) flat[pos] = e;
  }
}

// ---------------------------------------------------------------------------
// Kernel A4: pack W_hh (f32 [1024][256]) into f16 MFMA B-fragment order.
// Frag (nt 0..63, ks 0..7, lane 0..63): 8 f16 = W[nt*16+(l&15)][ks*32+(l>>4)*8 + j]
// ---------------------------------------------------------------------------
__global__ void wpack_kernel(const float* __restrict__ Whh,
                             _Float16* __restrict__ wpack) {
  int gid = blockIdx.x * 256 + threadIdx.x;  // 0..32767
  int nt = gid >> 9;
  int rem = gid & 511;
  int ks = rem >> 6;
  int l = rem & 63;
  int n = nt * 16 + (l & 15);
  int k = ks * 32 + (l >> 4) * 8;
  const float* src = Whh + (size_t)n * H_DIM + k;
  f4 v0 = *(const f4*)src;
  f4 v1 = *(const f4*)(src + 4);
  h8 wv = {(_Float16)v0.x, (_Float16)v0.y, (_Float16)v0.z, (_Float16)v0.w,
           (_Float16)v1.x, (_Float16)v1.y, (_Float16)v1.z, (_Float16)v1.w};
  *(h8*)(wpack + (size_t)gid * 8) = wv;
}

// ---------------------------------------------------------------------------
// Kernel A5: X f32 -> f16 elementwise convert (vectorized, grid-stride).
// ---------------------------------------------------------------------------
__global__ __launch_bounds__(256) void xcvt_kernel(const float* __restrict__ X,
                                                   _Float16* __restrict__ xh) {
  const int n8 = (T_DIM * B_DIM * D_DIM) / 8;  // 8388608
  int stride = gridDim.x * blockDim.x;
  for (int i = blockIdx.x * blockDim.x + threadIdx.x; i < n8; i += stride) {
    const float* s = X + (size_t)i * 8;
    f4 a = *(const f4*)s;
    f4 b = *(const f4*)(s + 4);
    h8 v = {(_Float16)a.x, (_Float16)a.y, (_Float16)a.z, (_Float16)a.w,
            (_Float16)b.x, (_Float16)b.y, (_Float16)b.z, (_Float16)b.w};
    *(h8*)(xh + (size_t)i * 8) = v;
  }
}

// ---------------------------------------------------------------------------
// Kernel A6: pack W_ih (f32 [1024][512]) into f16 MFMA B-fragment order.
// Frag (nt 0..63, ks 0..15, lane): 8 f16 = Wih[nt*16+(l&15)][ks*32+(l>>4)*8+j]
// Layout: wihp[((nt*16 + ks)*64 + l)*8 + j]  (1 MB total, L2-resident)
// ---------------------------------------------------------------------------
__global__ void wihpack_kernel(const float* __restrict__ Wih,
                               _Float16* __restrict__ wihp) {
  int gid = blockIdx.x * 256 + threadIdx.x;  // 0..65535
  int nt = gid >> 10;
  int ks = (gid >> 6) & 15;
  int l = gid & 63;
  int n = nt * 16 + (l & 15);
  int k = ks * 32 + (l >> 4) * 8;
  const float* src = Wih + (size_t)n * D_DIM + k;
  f4 v0 = *(const f4*)src;
  f4 v1 = *(const f4*)(src + 4);
  h8 wv = {(_Float16)v0.x, (_Float16)v0.y, (_Float16)v0.z, (_Float16)v0.w,
           (_Float16)v1.x, (_Float16)v1.y, (_Float16)v1.z, (_Float16)v1.w};
  *(h8*)(wihp + (size_t)gid * 8) = wv;
}

// ---------------------------------------------------------------------------
// Kernel B (new): zero-LDS zero-barrier direct-fragment GEMM.
// xw = xh(f16) @ Wih^T + bih + bhh. A-frags per-lane from xh (L2-hot via XCD
// swizzle), B-frags per-lane from wihp (1 MB, L2-resident). 16 waves/CU
// free-run; no barriers, no LDS.
// ---------------------------------------------------------------------------
#define BM 128
#define BN 128
#define BK 32

__global__ __launch_bounds__(256) void xw_gemm_direct(
    const _Float16* __restrict__ xh, const _Float16* __restrict__ wihp,
    const float* __restrict__ bih, const float* __restrict__ bhh,
    _Float16* __restrict__ xw) {
  const int tid = threadIdx.x;
  const int lane = tid & 63;
  const int wave = tid >> 6;
  const unsigned wg = blockIdx.x;
  const unsigned xcd = wg & 7u;
  const unsigned idx = wg >> 3;                      // 0..1023 per XCD
  const size_t m0 = (size_t)(xcd * 128u + (idx >> 3)) * BM;
  const int n0 = (int)(idx & 7u) * BN;
  const int wm = (wave & 1) * 64;
  const int wn = (wave >> 1) * 64;
  const int q = lane >> 4;
  const int r = lane & 15;

  f4 acc[4][4];
#pragma unroll
  for (int i = 0; i < 4; ++i)
#pragma unroll
    for (int j = 0; j < 4; ++j) { f4 z = {0.f, 0.f, 0.f, 0.f}; acc[i][j] = z; }

  const _Float16* aBase = xh + (m0 + (size_t)(wm + r)) * D_DIM + q * 8;
  const _Float16* bBase = wihp + ((size_t)(((n0 + wn) >> 4) * 16) * 64 + lane) * 8;

#pragma unroll 4
  for (int ks = 0; ks < 16; ++ks) {
    h8 af[4], bf[4];
#pragma unroll
    for (int mi = 0; mi < 4; ++mi)
      af[mi] = *(const h8*)(aBase + (size_t)mi * (16 * D_DIM) + ks * 32);
#pragma unroll
    for (int ni = 0; ni < 4; ++ni)
      bf[ni] = *(const h8*)(bBase + (size_t)(ni * 16 + ks) * (64 * 8));
#pragma unroll
    for (int mi = 0; mi < 4; ++mi)
#pragma unroll
      for (int ni = 0; ni < 4; ++ni)
        acc[mi][ni] = __builtin_amdgcn_mfma_f32_16x16x32_f16(af[mi], bf[ni], acc[mi][ni], 0, 0, 0);
  }

#pragma unroll
  for (int mi = 0; mi < 4; ++mi) {
#pragma unroll
    for (int ni = 0; ni < 4; ++ni) {
      int n = n0 + wn + ni * 16 + r;
      float bias = bih[n] + bhh[n];
#pragma unroll
      for (int reg = 0; reg < 4; ++reg) {
        size_t m = m0 + (size_t)(wm + mi * 16 + q * 4 + reg);
        xw[m * G_DIM + n] = (_Float16)(acc[mi][ni][reg] + bias);
      }
    }
  }
}

// ---------------------------------------------------------------------------
// Kernel B (fallback, old): xw = x @ W_ih^T + bias with inline f32->f16.
// Used only when the workspace is too small for xh/wihp.
// ---------------------------------------------------------------------------
__global__ __launch_bounds__(256) void xw_gemm_kernel(
    const float* __restrict__ X, const float* __restrict__ Wih,
    const float* __restrict__ bih, const float* __restrict__ bhh,
    _Float16* __restrict__ xw) {
  __shared__ _Float16 As[BM * BK];
  __shared__ _Float16 Bs[BN * BK];
  const int tid = threadIdx.x;
  const int lane = tid & 63;
  const int wave = tid >> 6;
  const unsigned wg = blockIdx.x;
  const unsigned xcd = wg & 7u;
  const unsigned idx = wg >> 3;
  const size_t m0 = (size_t)(xcd * 128u + (idx >> 3)) * BM;
  const int n0 = (int)(idx & 7u) * BN;
  const int wm = (wave & 1) * 64;
  const int wn = (wave >> 1) * 64;
  const int q = lane >> 4;
  const int r = lane & 15;

  f4 acc[4][4];
#pragma unroll
  for (int i = 0; i < 4; ++i)
#pragma unroll
    for (int j = 0; j < 4; ++j) { f4 z = {0.f, 0.f, 0.f, 0.f}; acc[i][j] = z; }

  const int srow = tid >> 1;
  const int kh = (tid & 1) * 16;

  for (int k0 = 0; k0 < D_DIM; k0 += BK) {
    const float* ax = X + (m0 + (size_t)srow) * D_DIM + k0 + kh;
    const float* bx = Wih + ((size_t)(n0 + srow)) * D_DIM + k0 + kh;
    f4 a0 = *(const f4*)(ax);
    f4 a1 = *(const f4*)(ax + 4);
    f4 a2 = *(const f4*)(ax + 8);
    f4 a3 = *(const f4*)(ax + 12);
    f4 b0 = *(const f4*)(bx);
    f4 b1 = *(const f4*)(bx + 4);
    f4 b2 = *(const f4*)(bx + 8);
    f4 b3 = *(const f4*)(bx + 12);
    h8 ha0 = {(_Float16)a0.x, (_Float16)a0.y, (_Float16)a0.z, (_Float16)a0.w,
              (_Float16)a1.x, (_Float16)a1.y, (_Float16)a1.z, (_Float16)a1.w};
    h8 ha1 = {(_Float16)a2.x, (_Float16)a2.y, (_Float16)a2.z, (_Float16)a2.w,
              (_Float16)a3.x, (_Float16)a3.y, (_Float16)a3.z, (_Float16)a3.w};
    h8 hb0 = {(_Float16)b0.x, (_Float16)b0.y, (_Float16)b0.z, (_Float16)b0.w,
              (_Float16)b1.x, (_Float16)b1.y, (_Float16)b1.z, (_Float16)b1.w};
    h8 hb1 = {(_Float16)b2.x, (_Float16)b2.y, (_Float16)b2.z, (_Float16)b2.w,
              (_Float16)b3.x, (_Float16)b3.y, (_Float16)b3.z, (_Float16)b3.w};
    *(h8*)(As + srow * BK + kh) = ha0;
    *(h8*)(As + srow * BK + kh + 8) = ha1;
    *(h8*)(Bs + srow * BK + kh) = hb0;
    *(h8*)(Bs + srow * BK + kh + 8) = hb1;
    __syncthreads();

    h8 af[4], bf[4];
#pragma unroll
    for (int mi = 0; mi < 4; ++mi)
      af[mi] = *(const h8*)(As + (wm + mi * 16 + r) * BK + q * 8);
#pragma unroll
    for (int ni = 0; ni < 4; ++ni)
      bf[ni] = *(const h8*)(Bs + (wn + ni * 16 + r) * BK + q * 8);
#pragma unroll
    for (int mi = 0; mi < 4; ++mi)
#pragma unroll
      for (int ni = 0; ni < 4; ++ni)
        acc[mi][ni] = __builtin_amdgcn_mfma_f32_16x16x32_f16(af[mi], bf[ni], acc[mi][ni], 0, 0, 0);
    __syncthreads();
  }

#pragma unroll
  for (int mi = 0; mi < 4; ++mi) {
#pragma unroll
    for (int ni = 0; ni < 4; ++ni) {
      int n = n0 + wn + ni * 16 + r;
      float bias = bih[n] + bhh[n];
#pragma unroll
      for (int reg = 0; reg < 4; ++reg) {
        size_t m = m0 + (size_t)(wm + mi * 16 + q * 4 + reg);
        xw[m * G_DIM + n] = (_Float16)(acc[mi][ni][reg] + bias);
      }
    }
  }
}

// ---------------------------------------------------------------------------
// Kernel C: MFMA-lockstep segment-parallel LSTM scan.
// 256 blocks x 512 thr (1 block/CU, 2 waves/SIMD pinned -> 256-VGPR budget).
// W residency: ks0-1 in regs, ks2 in LDS (64 KB), ks3-7 streamed from L2.
// xw rows staged per step via global_load_lds width 16 with NT cache policy
// (aux=2) so the 268 MB xw stream does NOT evict wpack from L2.
// ---------------------------------------------------------------------------
__device__ __forceinline__ float sigmf(float x) {
  return __builtin_amdgcn_rcpf(1.f + __expf(-x));
}
__device__ __forceinline__ float tanhf_(float x) {
  return 2.f * __builtin_amdgcn_rcpf(1.f + __expf(-2.f * x)) - 1.f;
}
__device__ __forceinline__ f4 MF(h8 a, h8 b, f4 c) {
  return __builtin_amdgcn_mfma_f32_16x16x32_f16(a, b, c, 0, 0, 0);
}

#define WPKp(g, j, ks) \
  ((const h8*)(wpack + (((size_t)((((g)*16 + 2*w + (j)) * 8 + (ks))) * 64 + l) * 8)))
#define ARD(mt, ks) (*(const h8*)(Hbuf + (16*(mt) + r16) * HSTR + (ks)*32 + q*8))

#define MFK_REG(KS) do {                                                   \
  h8 a0_ = ARD(0, KS), a1_ = ARD(1, KS);                                   \
  _Pragma("unroll") for (int g = 0; g < 4; ++g)                            \
  _Pragma("unroll") for (int j = 0; j < 2; ++j) {                          \
    acc[0][g][j] = MF(a0_, wr[g][j][KS], acc[0][g][j]);                    \
    acc[1][g][j] = MF(a1_, wr[g][j][KS], acc[1][g][j]); }                  \
} while (0)

#define MFK_W2() do {                                                      \
  h8 a0_ = ARD(0, 2), a1_ = ARD(1, 2);                                     \
  _Pragma("unroll") for (int g = 0; g < 4; ++g)                            \
  _Pragma("unroll") for (int j = 0; j < 2; ++j) {                          \
    h8 b_ = *(const h8*)(Wlds + (size_t)((((g)*16 + 2*w + (j)) * 64 + l)) * 8); \
    acc[0][g][j] = MF(a0_, b_, acc[0][g][j]);                              \
    acc[1][g][j] = MF(a1_, b_, acc[1][g][j]); }                            \
} while (0)

#define MFK_S(BUF, KS) do {                                                \
  h8 a0_ = ARD(0, KS), a1_ = ARD(1, KS);                                   \
  _Pragma("unroll") for (int g = 0; g < 4; ++g)                            \
  _Pragma("unroll") for (int j = 0; j < 2; ++j) {                          \
    acc[0][g][j] = MF(a0_, BUF[g][j], acc[0][g][j]);                       \
    acc[1][g][j] = MF(a1_, BUF[g][j], acc[1][g][j]); }                     \
} while (0)

#define LOAD_S(BUF, KS) do {                                               \
  _Pragma("unroll") for (int g = 0; g < 4; ++g)                            \
  _Pragma("unroll") for (int j = 0; j < 2; ++j)                            \
    BUF[g][j] = *WPKp(g, j, KS);                                           \
} while (0)

#define XRD(MT, G, J) do {                                                 \
  f4 xv;                                                                   \
  int rb_ = 16*(MT) + q*4;                                                 \
  int nn_ = (G)*256 + w*32 + 16*(J) + r16;                                 \
  xv.x = (float)xwlds[(rb_+0)*XSTR + nn_];                                 \
  xv.y = (float)xwlds[(rb_+1)*XSTR + nn_];                                 \
  xv.z = (float)xwlds[(rb_+2)*XSTR + nn_];                                 \
  xv.w = (float)xwlds[(rb_+3)*XSTR + nn_];                                 \
  acc[MT][G][J] += xv; } while (0)

#define CONTROL_STEP do {                                                     \
  int m = tid;                                                                \
  bool aliv = alivef[m] != 0;                                                 \
  if (aliv) {                                                                 \
    unsigned oi = outix[m];                                                   \
    if (oi != 0xFFFFFFFFu) {                                                  \
      float s = bp;                                                           \
      _Pragma("unroll") for (int ww = 0; ww < 8; ++ww) s += pbuf[ww][m];      \
      __builtin_nontemporal_store(s, &out[oi]);                               \
    }                                                                         \
  }                                                                           \
  bool cont = aliv && (tcur[m] + 1 < tend[m]);                                \
  bool need = aliv && !cont;                                                  \
  unsigned long long bal = __ballot(need);                                    \
  if (cont) {                                                                 \
    int t = tcur[m] + 1;                                                      \
    tcur[m] = t; keepm[m] = 1.f;                                              \
    unsigned row = (unsigned)t * 32u + (unsigned)bcol[m];                     \
    trowB[m] = row * 2048u; outix[m] = row;                                   \
  }                                                                           \
  if (bal) {                                                                  \
    unsigned cntp = (unsigned)__popcll(bal);                                  \
    int ldr = (int)__ffsll(bal) - 1;                                          \
    unsigned basep = 0;                                                       \
    if ((tid & 63) == ldr) basep = atomicAdd(ctr, cntp);                      \
    basep = __shfl(basep, ldr);                                               \
    if (need) {                                                               \
      unsigned idx = basep +                                                  \
          (unsigned)__popcll(bal & ((1ull << (tid & 63)) - 1ull));            \
      if (idx < nseg) {                                                       \
        uint2 sg = flat[idx];                                                 \
        int t0s = (int)(sg.x & 0xFFFFu); int bb = (int)(sg.x >> 16);          \
        tcur[m] = t0s; tend[m] = (int)sg.y; bcol[m] = bb; keepm[m] = 0.f;     \
        unsigned row = (unsigned)t0s * 32u + (unsigned)bb;                    \
        trowB[m] = row * 2048u; outix[m] = row;                               \
        h8 zz = {0,0,0,0,0,0,0,0};                                            \
        _Pragma("unroll") for (int i2 = 0; i2 < 33; ++i2)                     \
          *(h8*)(Hbuf + (size_t)m * HSTR + i2 * 8) = zz;                      \
      } else {                                                                \
        alivef[m] = 0; outix[m] = 0xFFFFFFFFu; trowB[m] = 0;                  \
        keepm[m] = 0.f;                                                       \
      }                                                                       \
    }                                                                         \
  }                                                                           \
} while (0)

__global__ __attribute__((amdgpu_flat_work_group_size(512, 512),
                          amdgpu_waves_per_eu(2, 2)))
void lstm_scan_mfma(
    const _Float16* __restrict__ xw,
    const _Float16* __restrict__ wpack,
    const float* __restrict__ Wproj,
    const float* __restrict__ bproj,
    const uint2* __restrict__ flat,
    unsigned* __restrict__ meta,
    float* __restrict__ out) {
  __shared__ __align__(16) _Float16 Wlds[64 * 64 * 8];      // 64 KB (ks 2)
  __shared__ __align__(16) _Float16 xwlds[32 * XSTR];       // 66.3 KB
  __shared__ __align__(16) _Float16 Hbuf[32 * HSTR];        // 16.9 KB
  __shared__ __align__(16) float pbuf[8][32];               // 1 KB
  __shared__ __align__(16) unsigned trowB[32];
  __shared__ __align__(16) float keepm[32];
  __shared__ unsigned outix[32];
  __shared__ int tcur[32], tend[32], bcol[32], alivef[32];

  const int tid = threadIdx.x;
  const int l = tid & 63;
  const int w = tid >> 6;        // wave 0..7
  const int q = l >> 4;
  const int r16 = l & 15;
  const char* xwc = (const char*)xw;
  unsigned* ctr = meta;
  const unsigned nseg = meta[1];

  // init: LDS weights (kstep 2), zero Hbuf
  for (int it = 0; it < 16; ++it) {
    int idx = it * 512 + tid;
    int nt = idx >> 6;
    int ll = idx & 63;
    *(h8*)(Wlds + (size_t)idx * 8) =
        *(const h8*)(wpack + (((size_t)(nt * 8 + 2)) * 64 + ll) * 8);
  }
  for (int i = tid; i < 32 * HSTR / 8; i += 512) {
    h8 z = {0,0,0,0,0,0,0,0};
    *(h8*)(Hbuf + (size_t)i * 8) = z;
  }
  // register weights: ksteps 0..1, all 8 n-tiles of this wave (64 VGPR)
  h8 wr[4][2][2];
#pragma unroll
  for (int g = 0; g < 4; ++g)
#pragma unroll
    for (int j = 0; j < 2; ++j)
#pragma unroll
      for (int ks = 0; ks < 2; ++ks)
        wr[g][j][ks] = *WPKp(g, j, ks);

  const float wpv0 = Wproj[32 * w + r16];
  const float wpv1 = Wproj[32 * w + 16 + r16];
  const float bp = bproj[0];
  if (tid < 32) {
    alivef[tid] = 1; tcur[tid] = 0; tend[tid] = 0; bcol[tid] = 0;
    outix[tid] = 0xFFFFFFFFu; trowB[tid] = 0; keepm[tid] = 0.f;
  }
  float cst[16];
#pragma unroll
  for (int i = 0; i < 16; ++i) cst[i] = 0.f;
  __syncthreads();
  if (tid < 32) CONTROL_STEP;  // initial segment pulls
  int nalive = __syncthreads_count(tid < 32 ? alivef[tid] : 0);

  while (nalive > 0) {
    // --- issue xw staging for THIS step (NT: evict-first, keep wpack hot) ---
#pragma unroll
    for (int rnd = 0; rnd < 8; ++rnd) {
      int c = rnd * 8 + w;
      unsigned rowB = trowB[c >> 1];
      const char* src = xwc + (size_t)rowB + (size_t)((c & 1) * 1024) + (size_t)l * 16;
      _Float16* dst = xwlds + (size_t)(c >> 1) * XSTR + (c & 1) * 512;
      __builtin_amdgcn_global_load_lds((const uint32_t*)src, (uint32_t*)dst, 16, 0, 2);
    }

    f4 z4 = {0.f, 0.f, 0.f, 0.f};
    f4 acc[2][4][2];
#pragma unroll
    for (int mt = 0; mt < 2; ++mt)
#pragma unroll
      for (int g = 0; g < 4; ++g)
#pragma unroll
        for (int j = 0; j < 2; ++j) acc[mt][g][j] = z4;
    h8 sA[4][2], sB[4][2];

    // stream schedule: each buffer consumed >=32 MFMA after its issue
    LOAD_S(sA, 3); LOAD_S(sB, 4);
    MFK_REG(0);
    MFK_REG(1);
    MFK_W2();
    MFK_S(sA, 3); LOAD_S(sA, 5);
    MFK_S(sB, 4); LOAD_S(sB, 6);
    MFK_S(sA, 5); LOAD_S(sA, 7);
    MFK_S(sB, 6);
    MFK_S(sA, 7);

    __syncthreads();  // B0: Hbuf reads done; xw staging drained

    // xw add from LDS
    XRD(0, 0, 0); XRD(0, 0, 1);
    XRD(0, 1, 0); XRD(0, 1, 1);
    XRD(0, 2, 0); XRD(0, 2, 1);
    XRD(0, 3, 0); XRD(0, 3, 1);
    XRD(1, 0, 0); XRD(1, 0, 1);
    XRD(1, 1, 0); XRD(1, 1, 1);
    XRD(1, 2, 0); XRD(1, 2, 1);
    XRD(1, 3, 0); XRD(1, 3, 1);

    // nonlinearity + state update + h-write + projection partial (wave-local)
    f4 kp0 = *(const f4*)&keepm[q * 4];
    f4 kp1 = *(const f4*)&keepm[16 + q * 4];
    float pr[8];
#pragma unroll
    for (int r = 0; r < 4; ++r) {
      {
        float gi = sigmf(acc[0][0][0][r]);
        float gf = sigmf(acc[0][1][0][r]);
        float gg = tanhf_(acc[0][2][0][r]);
        float go = sigmf(acc[0][3][0][r]);
        float cn = gf * (cst[r] * kp0[r]) + gi * gg;
        cst[r] = cn;
        float hv = go * tanhf_(cn);
        Hbuf[(q * 4 + r) * HSTR + 32 * w + r16] = (_Float16)hv;
        pr[r] = hv * wpv0;
      }
      {
        float gi = sigmf(acc[0][0][1][r]);
        float gf = sigmf(acc[0][1][1][r]);
        float gg = tanhf_(acc[0][2][1][r]);
        float go = sigmf(acc[0][3][1][r]);
        float cn = gf * (cst[4 + r] * kp0[r]) + gi * gg;
        cst[4 + r] = cn;
        float hv = go * tanhf_(cn);
        Hbuf[(q * 4 + r) * HSTR + 32 * w + 16 + r16] = (_Float16)hv;
        pr[r] += hv * wpv1;
      }
    }
#pragma unroll
    for (int r = 0; r < 4; ++r) {
      {
        float gi = sigmf(acc[1][0][0][r]);
        float gf = sigmf(acc[1][1][0][r]);
        float gg = tanhf_(acc[1][2][0][r]);
        float go = sigmf(acc[1][3][0][r]);
        float cn = gf * (cst[8 + r] * kp1[r]) + gi * gg;
        cst[8 + r] = cn;
        float hv = go * tanhf_(cn);
        Hbuf[(16 + q * 4 + r) * HSTR + 32 * w + r16] = (_Float16)hv;
        pr[4 + r] = hv * wpv0;
      }
      {
        float gi = sigmf(acc[1][0][1][r]);
        float gf = sigmf(acc[1][1][1][r]);
        float gg = tanhf_(acc[1][2][1][r]);
        float go = sigmf(acc[1][3][1][r]);
        float cn = gf * (cst[12 + r] * kp1[r]) + gi * gg;
        cst[12 + r] = cn;
        float hv = go * tanhf_(cn);
        Hbuf[(16 + q * 4 + r) * HSTR + 32 * w + 16 + r16] = (_Float16)hv;
        pr[4 + r] += hv * wpv1;
      }
    }
#pragma unroll
    for (int jj = 0; jj < 8; ++jj) {
      pr[jj] += __shfl_xor(pr[jj], 1);
      pr[jj] += __shfl_xor(pr[jj], 2);
      pr[jj] += __shfl_xor(pr[jj], 4);
      pr[jj] += __shfl_xor(pr[jj], 8);
    }
    if (r16 == 0) {
#pragma unroll
      for (int jj = 0; jj < 8; ++jj)
        pbuf[w][16 * (jj >> 2) + q * 4 + (jj & 3)] = pr[jj];
    }

    __syncthreads();  // B1
    if (tid < 32) CONTROL_STEP;
    nalive = __syncthreads_count(tid < 32 ? alivef[tid] : 0);
  }
}

// ---------------------------------------------------------------------------
extern "C" void kernel_launch(void* const* d_in, const int* in_sizes, int n_in,
                              void* d_out, int out_size, void* d_ws, size_t ws_size,
                              hipStream_t stream) {
  const float* x = (const float*)d_in[0];
  const int* reset = (const int*)d_in[1];
  const float* Wih = (const float*)d_in[2];
  const float* Whh = (const float*)d_in[3];
  const float* bih = (const float*)d_in[4];
  const float* bhh = (const float*)d_in[5];
  const float* Wproj = (const float*)d_in[6];
  const float* bproj = (const float*)d_in[7];
  float* out = (float*)d_out;

  char* ws = (char*)d_ws;
  _Float16* xw = (_Float16*)ws;                           // 268435456 B
  unsigned* starts = (unsigned*)(ws + 268435456ULL);      // 524288 B
  unsigned* segcnt = (unsigned*)(ws + 268959744ULL);      // 128 B
  uint2* flat = (uint2*)(ws + 268959872ULL);              // 1048576 B
  _Float16* wpack = (_Float16*)(ws + 270008448ULL);       // 524288 B
  unsigned* meta = (unsigned*)(ws + 270532736ULL);        // 8 B
  // extended region (guarded by ws_size):
  _Float16* xh = (_Float16*)(ws + 270532864ULL);          // 134217728 B
  _Float16* wihp = (_Float16*)(ws + 404750592ULL);        // 1048576 B
  const bool big = ws_size >= 405799168ULL;
  // scratch aliased into xw region (consumed before xw is written):
  uint2* flat2 = (uint2*)ws;                              // 1048576 B

  hipLaunchKernelGGL(seg_build_kernel, dim3(32), dim3(256), 0, stream,
                     reset, starts, segcnt);
  hipLaunchKernelGGL(seg_flat_kernel, dim3(32), dim3(256), 0, stream,
                     starts, segcnt, flat2, meta);
  hipLaunchKernelGGL(seg_sort_kernel, dim3(1), dim3(1024), 0, stream,
                     flat2, flat, meta);
  hipLaunchKernelGGL(wpack_kernel, dim3(128), dim3(256), 0, stream,
                     Whh, wpack);
  if (big) {
    hipLaunchKernelGGL(xcvt_kernel, dim3(2048), dim3(256), 0, stream, x, xh);
    hipLaunchKernelGGL(wihpack_kernel, dim3(256), dim3(256), 0, stream,
                       Wih, wihp);
    hipLaunchKernelGGL(xw_gemm_direct, dim3(8192), dim3(256), 0, stream,
                       xh, wihp, bih, bhh, xw);
  } else {
    hipLaunchKernelGGL(xw_gemm_kernel, dim3(8192), dim3(256), 0, stream,
                       x, Wih, bih, bhh, xw);
  }
  hipLaunchKernelGGL(lstm_scan_mfma, dim3(256), dim3(512), 0, stream,
                     xw, wpack, Wproj, bproj, flat, meta, out);
}

// Round 6
// 1168.277 us; speedup vs baseline: 1.1279x; 1.1279x over previous
//
#include <hip/hip_runtime.h>
#include <cstdint>
#include <cstddef>

#define T_DIM 4096
#define B_DIM 32
#define D_DIM 512
#define H_DIM 256
#define G_DIM 1024  // 4*H
#define HSTR 264    // padded H-row stride in f16 elems (2-way LDS aliasing = free)
#define XSTR 1036   // padded xw-row stride in f16 elems (2072 B)
#define NBUCK 64    // LPT sort buckets (lengths >= NBUCK share the top bucket)

typedef _Float16 h8 __attribute__((ext_vector_type(8)));
typedef float f4 __attribute__((ext_vector_type(4)));

// ---------------------------------------------------------------------------
// Kernel A: per-batch segment extraction (atomic-free).
// ---------------------------------------------------------------------------
__global__ void seg_build_kernel(const int* __restrict__ reset,
                                 unsigned* __restrict__ starts,
                                 unsigned* __restrict__ segcnt) {
  __shared__ unsigned cnts[256];
  __shared__ unsigned offs[256];
  const int b = blockIdx.x;
  const int tid = threadIdx.x;
  const int t0 = tid * 16;
  unsigned c = 0;
  for (int e = 0; e < 16; ++e) {
    int t = t0 + e;
    bool pred = (t == 0) || (reset[t * B_DIM + b] != 0);
    c += pred ? 1u : 0u;
  }
  cnts[tid] = c;
  __syncthreads();
  if (tid == 0) {
    unsigned run = 0;
    for (int i = 0; i < 256; ++i) { unsigned v = cnts[i]; offs[i] = run; run += v; }
    segcnt[b] = run;
  }
  __syncthreads();
  unsigned o = (unsigned)b * 4096u + offs[tid];
  for (int e = 0; e < 16; ++e) {
    int t = t0 + e;
    bool pred = (t == 0) || (reset[t * B_DIM + b] != 0);
    if (pred) { starts[o++] = (unsigned)t; }
  }
}

// ---------------------------------------------------------------------------
// Kernel A2: flatten per-batch segment lists into one UNSORTED queue (flat2).
// ---------------------------------------------------------------------------
__global__ void seg_flat_kernel(const unsigned* __restrict__ starts,
                                const unsigned* __restrict__ segcnt,
                                uint2* __restrict__ flat2,
                                unsigned* __restrict__ meta) {
  __shared__ unsigned offs;
  const int b = blockIdx.x;
  const int tid = threadIdx.x;
  if (tid == 0) {
    unsigned o = 0;
    for (int i = 0; i < b; ++i) o += segcnt[i];
    offs = o;
    if (b == 31) meta[1] = o + segcnt[31];
    if (b == 0) meta[0] = 0u;
  }
  __syncthreads();
  const unsigned cnt = segcnt[b];
  const unsigned off = offs;
  for (unsigned s = tid; s < cnt; s += 256) {
    unsigned t0 = starts[b * 4096u + s];
    unsigned t1 = (s + 1 < cnt) ? starts[b * 4096u + s + 1] : 4096u;
    flat2[off + s] = make_uint2(t0 | ((unsigned)b << 16), t1);
  }
}

// ---------------------------------------------------------------------------
// Kernel A3: LPT counting sort, single block, wave-aggregated atomics.
// ---------------------------------------------------------------------------
__global__ void seg_sort_kernel(const uint2* __restrict__ flat2,
                                uint2* __restrict__ flat,
                                const unsigned* __restrict__ meta) {
  __shared__ unsigned lh[NBUCK];
  __shared__ unsigned cur[NBUCK];
  const unsigned nseg = meta[1];
  const int tid = threadIdx.x;
  const int lane = tid & 63;
  if (tid < NBUCK) lh[tid] = 0u;
  __syncthreads();
  for (unsigned base = 0; base < nseg; base += 1024) {
    unsigned i = base + tid;
    bool act = i < nseg;
    unsigned bk = 0u;
    if (act) {
      uint2 e = flat2[i];
      bk = min(e.y - (e.x & 0xFFFFu), (unsigned)NBUCK) - 1u;
    }
    unsigned long long rem = __ballot(act);
    while (rem) {
      int ld = (int)__ffsll((unsigned long long)rem) - 1;
      unsigned lbk = __shfl(bk, ld);
      unsigned long long meq = __ballot(act && bk == lbk);
      if (lane == ld) atomicAdd(&lh[lbk], (unsigned)__popcll(meq));
      rem &= ~meq;
    }
  }
  __syncthreads();
  if (tid == 0) {
    unsigned run = 0;
    for (int k = NBUCK - 1; k >= 0; --k) { cur[k] = run; run += lh[k]; }
  }
  __syncthreads();
  for (unsigned base = 0; base < nseg; base += 1024) {
    unsigned i = base + tid;
    bool act = i < nseg;
    uint2 e = make_uint2(0u, 0u);
    unsigned bk = 0u;
    if (act) {
      e = flat2[i];
      bk = min(e.y - (e.x & 0xFFFFu), (unsigned)NBUCK) - 1u;
    }
    unsigned long long rem = __ballot(act);
    unsigned pos = 0u;
    while (rem) {
      int ld = (int)__ffsll((unsigned long long)rem) - 1;
      unsigned lbk = __shfl(bk, ld);
      unsigned long long meq = __ballot(act && bk == lbk);
      unsigned bs = 0u;
      if (lane == ld) bs = atomicAdd(&cur[lbk], (unsigned)__popcll(meq));
      bs = __shfl(bs, ld);
      if (act && bk == lbk)
        pos = bs + (unsigned)__popcll(meq & ((1ull << lane) - 1ull));
      rem &= ~meq;
    }
    if (act) flat[pos] = e;
  }
}

// ---------------------------------------------------------------------------
// Kernel A4: pack W_hh (f32 [1024][256]) into f16 MFMA B-fragment order.
// Frag (nt 0..63, ks 0..7, lane 0..63): 8 f16 = W[nt*16+(l&15)][ks*32+(l>>4)*8 + j]
// ---------------------------------------------------------------------------
__global__ void wpack_kernel(const float* __restrict__ Whh,
                             _Float16* __restrict__ wpack) {
  int gid = blockIdx.x * 256 + threadIdx.x;  // 0..32767
  int nt = gid >> 9;
  int rem = gid & 511;
  int ks = rem >> 6;
  int l = rem & 63;
  int n = nt * 16 + (l & 15);
  int k = ks * 32 + (l >> 4) * 8;
  const float* src = Whh + (size_t)n * H_DIM + k;
  f4 v0 = *(const f4*)src;
  f4 v1 = *(const f4*)(src + 4);
  h8 wv = {(_Float16)v0.x, (_Float16)v0.y, (_Float16)v0.z, (_Float16)v0.w,
           (_Float16)v1.x, (_Float16)v1.y, (_Float16)v1.z, (_Float16)v1.w};
  *(h8*)(wpack + (size_t)gid * 8) = wv;
}

// ---------------------------------------------------------------------------
// Kernel A5: X f32 -> f16 elementwise convert (vectorized, grid-stride).
// ---------------------------------------------------------------------------
__global__ __launch_bounds__(256) void xcvt_kernel(const float* __restrict__ X,
                                                   _Float16* __restrict__ xh) {
  const int n8 = (T_DIM * B_DIM * D_DIM) / 8;  // 8388608
  int stride = gridDim.x * blockDim.x;
  for (int i = blockIdx.x * blockDim.x + threadIdx.x; i < n8; i += stride) {
    const float* s = X + (size_t)i * 8;
    f4 a = *(const f4*)s;
    f4 b = *(const f4*)(s + 4);
    h8 v = {(_Float16)a.x, (_Float16)a.y, (_Float16)a.z, (_Float16)a.w,
            (_Float16)b.x, (_Float16)b.y, (_Float16)b.z, (_Float16)b.w};
    *(h8*)(xh + (size_t)i * 8) = v;
  }
}

// ---------------------------------------------------------------------------
// Kernel A6: W_ih f32 [1024][512] -> f16 row-major copy (1 MB, L2-resident).
// ---------------------------------------------------------------------------
__global__ __launch_bounds__(256) void whcvt_kernel(const float* __restrict__ Wih,
                                                    _Float16* __restrict__ whp) {
  int i = blockIdx.x * 256 + threadIdx.x;  // 0..65535 (x8 elems)
  const float* s = Wih + (size_t)i * 8;
  f4 a = *(const f4*)s;
  f4 b = *(const f4*)(s + 4);
  h8 v = {(_Float16)a.x, (_Float16)a.y, (_Float16)a.z, (_Float16)a.w,
          (_Float16)b.x, (_Float16)b.y, (_Float16)b.z, (_Float16)b.w};
  *(h8*)(whp + (size_t)i * 8) = v;
}

// ---------------------------------------------------------------------------
// Kernel B: m97-style f16 GEMM. xw = xh @ whp^T + bih + bhh.
// global_load_lds width-16 staging (no cvt in loop), ds_read_b128 fragments,
// BK=64, single-buffered 2-barrier loop, XCD-swizzled grid.
// ---------------------------------------------------------------------------
#define GBM 128
#define GBN 128
#define GBK 64

__global__ __launch_bounds__(256) void xw_gemm_f16(
    const _Float16* __restrict__ xh, const _Float16* __restrict__ whp,
    const float* __restrict__ bih, const float* __restrict__ bhh,
    _Float16* __restrict__ xw) {
  __shared__ __align__(16) _Float16 As[GBM * GBK];  // 16 KB
  __shared__ __align__(16) _Float16 Bs[GBN * GBK];  // 16 KB
  const int tid = threadIdx.x;
  const int lane = tid & 63;
  const int wave = tid >> 6;
  const unsigned wg = blockIdx.x;
  const unsigned xcd = wg & 7u;
  const unsigned idx = wg >> 3;                      // 0..1023 per XCD
  const size_t m0 = (size_t)(xcd * 128u + (idx >> 3)) * GBM;
  const int n0 = (int)(idx & 7u) * GBN;
  const int wm = (wave & 1) * 64;
  const int wn = (wave >> 1) * 64;
  const int q = lane >> 4;
  const int r = lane & 15;

  f4 acc[4][4];
#pragma unroll
  for (int i = 0; i < 4; ++i)
#pragma unroll
    for (int j = 0; j < 4; ++j) { f4 z = {0.f, 0.f, 0.f, 0.f}; acc[i][j] = z; }

  const char* aSrc = (const char*)xh + m0 * (D_DIM * 2);        // 1024 B rows
  const char* bSrc = (const char*)whp + (size_t)n0 * (D_DIM * 2);

  for (int k0 = 0; k0 < D_DIM; k0 += GBK) {
#pragma unroll
    for (int i = 0; i < 4; ++i) {
      int o = tid * 16 + i * 4096;  // linear LDS byte offset; 128 B per row
      int row = o >> 7;
      int colb = o & 127;
      __builtin_amdgcn_global_load_lds(
          (const uint32_t*)(aSrc + (size_t)row * (D_DIM * 2) + k0 * 2 + colb),
          (uint32_t*)((char*)As + o), 16, 0, 0);
      __builtin_amdgcn_global_load_lds(
          (const uint32_t*)(bSrc + (size_t)row * (D_DIM * 2) + k0 * 2 + colb),
          (uint32_t*)((char*)Bs + o), 16, 0, 0);
    }
    __syncthreads();  // drains vmcnt(0): staging complete

    h8 af[4][2], bf[4][2];
#pragma unroll
    for (int mi = 0; mi < 4; ++mi)
#pragma unroll
      for (int ks = 0; ks < 2; ++ks)
        af[mi][ks] = *(const h8*)(As + (wm + mi * 16 + r) * GBK + ks * 32 + q * 8);
#pragma unroll
    for (int ni = 0; ni < 4; ++ni)
#pragma unroll
      for (int ks = 0; ks < 2; ++ks)
        bf[ni][ks] = *(const h8*)(Bs + (wn + ni * 16 + r) * GBK + ks * 32 + q * 8);
#pragma unroll
    for (int ks = 0; ks < 2; ++ks)
#pragma unroll
      for (int mi = 0; mi < 4; ++mi)
#pragma unroll
        for (int ni = 0; ni < 4; ++ni)
          acc[mi][ni] = __builtin_amdgcn_mfma_f32_16x16x32_f16(
              af[mi][ks], bf[ni][ks], acc[mi][ni], 0, 0, 0);
    __syncthreads();  // tile consumed before next staging overwrites
  }

#pragma unroll
  for (int mi = 0; mi < 4; ++mi) {
#pragma unroll
    for (int ni = 0; ni < 4; ++ni) {
      int n = n0 + wn + ni * 16 + r;
      float bias = bih[n] + bhh[n];
#pragma unroll
      for (int reg = 0; reg < 4; ++reg) {
        size_t m = m0 + (size_t)(wm + mi * 16 + q * 4 + reg);
        xw[m * G_DIM + n] = (_Float16)(acc[mi][ni][reg] + bias);
      }
    }
  }
}

// ---------------------------------------------------------------------------
// Kernel B (fallback): old f32-input GEMM (only if workspace too small).
// ---------------------------------------------------------------------------
#define BM 128
#define BN 128
#define BK 32

__global__ __launch_bounds__(256) void xw_gemm_kernel(
    const float* __restrict__ X, const float* __restrict__ Wih,
    const float* __restrict__ bih, const float* __restrict__ bhh,
    _Float16* __restrict__ xw) {
  __shared__ _Float16 As[BM * BK];
  __shared__ _Float16 Bs[BN * BK];
  const int tid = threadIdx.x;
  const int lane = tid & 63;
  const int wave = tid >> 6;
  const unsigned wg = blockIdx.x;
  const unsigned xcd = wg & 7u;
  const unsigned idx = wg >> 3;
  const size_t m0 = (size_t)(xcd * 128u + (idx >> 3)) * BM;
  const int n0 = (int)(idx & 7u) * BN;
  const int wm = (wave & 1) * 64;
  const int wn = (wave >> 1) * 64;
  const int q = lane >> 4;
  const int r = lane & 15;

  f4 acc[4][4];
#pragma unroll
  for (int i = 0; i < 4; ++i)
#pragma unroll
    for (int j = 0; j < 4; ++j) { f4 z = {0.f, 0.f, 0.f, 0.f}; acc[i][j] = z; }

  const int srow = tid >> 1;
  const int kh = (tid & 1) * 16;

  for (int k0 = 0; k0 < D_DIM; k0 += BK) {
    const float* ax = X + (m0 + (size_t)srow) * D_DIM + k0 + kh;
    const float* bx = Wih + ((size_t)(n0 + srow)) * D_DIM + k0 + kh;
    f4 a0 = *(const f4*)(ax);
    f4 a1 = *(const f4*)(ax + 4);
    f4 a2 = *(const f4*)(ax + 8);
    f4 a3 = *(const f4*)(ax + 12);
    f4 b0 = *(const f4*)(bx);
    f4 b1 = *(const f4*)(bx + 4);
    f4 b2 = *(const f4*)(bx + 8);
    f4 b3 = *(const f4*)(bx + 12);
    h8 ha0 = {(_Float16)a0.x, (_Float16)a0.y, (_Float16)a0.z, (_Float16)a0.w,
              (_Float16)a1.x, (_Float16)a1.y, (_Float16)a1.z, (_Float16)a1.w};
    h8 ha1 = {(_Float16)a2.x, (_Float16)a2.y, (_Float16)a2.z, (_Float16)a2.w,
              (_Float16)a3.x, (_Float16)a3.y, (_Float16)a3.z, (_Float16)a3.w};
    h8 hb0 = {(_Float16)b0.x, (_Float16)b0.y, (_Float16)b0.z, (_Float16)b0.w,
              (_Float16)b1.x, (_Float16)b1.y, (_Float16)b1.z, (_Float16)b1.w};
    h8 hb1 = {(_Float16)b2.x, (_Float16)b2.y, (_Float16)b2.z, (_Float16)b2.w,
              (_Float16)b3.x, (_Float16)b3.y, (_Float16)b3.z, (_Float16)b3.w};
    *(h8*)(As + srow * BK + kh) = ha0;
    *(h8*)(As + srow * BK + kh + 8) = ha1;
    *(h8*)(Bs + srow * BK + kh) = hb0;
    *(h8*)(Bs + srow * BK + kh + 8) = hb1;
    __syncthreads();

    h8 af[4], bf[4];
#pragma unroll
    for (int mi = 0; mi < 4; ++mi)
      af[mi] = *(const h8*)(As + (wm + mi * 16 + r) * BK + q * 8);
#pragma unroll
    for (int ni = 0; ni < 4; ++ni)
      bf[ni] = *(const h8*)(Bs + (wn + ni * 16 + r) * BK + q * 8);
#pragma unroll
    for (int mi = 0; mi < 4; ++mi)
#pragma unroll
      for (int ni = 0; ni < 4; ++ni)
        acc[mi][ni] = __builtin_amdgcn_mfma_f32_16x16x32_f16(af[mi], bf[ni], acc[mi][ni], 0, 0, 0);
    __syncthreads();
  }

#pragma unroll
  for (int mi = 0; mi < 4; ++mi) {
#pragma unroll
    for (int ni = 0; ni < 4; ++ni) {
      int n = n0 + wn + ni * 16 + r;
      float bias = bih[n] + bhh[n];
#pragma unroll
      for (int reg = 0; reg < 4; ++reg) {
        size_t m = m0 + (size_t)(wm + mi * 16 + q * 4 + reg);
        xw[m * G_DIM + n] = (_Float16)(acc[mi][ni][reg] + bias);
      }
    }
  }
}

// ---------------------------------------------------------------------------
// Kernel C: MFMA-lockstep segment-parallel LSTM scan — 16-wave / 1024-thread
// form (fits the 128-VGPR budget: acc 32 + wr 32 + stream 32 + cst 8 ~ 125,
// NO spills; round 3-5 taught that the 8-wave form demands ~190 live regs and
// the allocator spills/remats ~500 MB/dispatch instead of allocating 256).
// Wave w owns n-tiles {g*16+w} -> gates i,f,g,o for hh in [16w,16w+16).
// W residency: ks0-1 in regs (32 VGPR), ks2 in LDS (64 KB), ks3-7 streamed
// from L2 via two rotating buffers. xw rows staged per step into padded LDS
// via global_load_lds width 16 (verified R3/R4); ballot-aggregated pulls.
// ---------------------------------------------------------------------------
__device__ __forceinline__ float sigmf(float x) {
  return __builtin_amdgcn_rcpf(1.f + __expf(-x));
}
__device__ __forceinline__ float tanhf_(float x) {
  return 2.f * __builtin_amdgcn_rcpf(1.f + __expf(-2.f * x)) - 1.f;
}
__device__ __forceinline__ f4 MF(h8 a, h8 b, f4 c) {
  return __builtin_amdgcn_mfma_f32_16x16x32_f16(a, b, c, 0, 0, 0);
}

// n-tile of gate g for wave w is nt = g*16 + w
#define WPK16(g, ks) \
  ((const h8*)(wpack + (((size_t)(((g)*16 + w) * 8 + (ks))) * 64 + l) * 8))
#define ARD(mt, ks) (*(const h8*)(Hbuf + (16*(mt) + r16) * HSTR + (ks)*32 + q*8))

#define MFK_REG(KS) do {                                                   \
  h8 a0_ = ARD(0, KS), a1_ = ARD(1, KS);                                   \
  _Pragma("unroll") for (int g = 0; g < 4; ++g) {                          \
    acc[0][g] = MF(a0_, wr[g][KS], acc[0][g]);                             \
    acc[1][g] = MF(a1_, wr[g][KS], acc[1][g]); }                           \
} while (0)

#define MFK_W2() do {                                                      \
  h8 a0_ = ARD(0, 2), a1_ = ARD(1, 2);                                     \
  _Pragma("unroll") for (int g = 0; g < 4; ++g) {                          \
    h8 b_ = *(const h8*)(Wlds + (size_t)((((g)*16 + w) * 64 + l)) * 8);    \
    acc[0][g] = MF(a0_, b_, acc[0][g]);                                    \
    acc[1][g] = MF(a1_, b_, acc[1][g]); }                                  \
} while (0)

#define MFK_S(BUF, KS) do {                                                \
  h8 a0_ = ARD(0, KS), a1_ = ARD(1, KS);                                   \
  _Pragma("unroll") for (int g = 0; g < 4; ++g) {                          \
    acc[0][g] = MF(a0_, BUF[g], acc[0][g]);                                \
    acc[1][g] = MF(a1_, BUF[g], acc[1][g]); }                              \
} while (0)

#define LOAD_S(BUF, KS) do {                                               \
  _Pragma("unroll") for (int g = 0; g < 4; ++g)                            \
    BUF[g] = *WPK16(g, KS);                                                \
} while (0)

// xw add from LDS: rows 16*MT + q*4 + reg, col n = G*256 + hh
#define XRD(MT, G) do {                                                    \
  f4 xv;                                                                   \
  int rb_ = 16*(MT) + q*4;                                                 \
  int nn_ = (G)*256 + hh;                                                  \
  xv.x = (float)xwlds[(rb_+0)*XSTR + nn_];                                 \
  xv.y = (float)xwlds[(rb_+1)*XSTR + nn_];                                 \
  xv.z = (float)xwlds[(rb_+2)*XSTR + nn_];                                 \
  xv.w = (float)xwlds[(rb_+3)*XSTR + nn_];                                 \
  acc[MT][G] += xv; } while (0)

#define CONTROL_STEP do {                                                     \
  int m = tid;                                                                \
  bool aliv = alivef[m] != 0;                                                 \
  if (aliv) {                                                                 \
    unsigned oi = outix[m];                                                   \
    if (oi != 0xFFFFFFFFu) {                                                  \
      float s = bp;                                                           \
      _Pragma("unroll") for (int ww = 0; ww < 16; ++ww) s += pbuf[ww][m];     \
      __builtin_nontemporal_store(s, &out[oi]);                               \
    }                                                                         \
  }                                                                           \
  bool cont = aliv && (tcur[m] + 1 < tend[m]);                                \
  bool need = aliv && !cont;                                                  \
  unsigned long long bal = __ballot(need);                                    \
  if (cont) {                                                                 \
    int t = tcur[m] + 1;                                                      \
    tcur[m] = t; keepm[m] = 1.f;                                              \
    unsigned row = (unsigned)t * 32u + (unsigned)bcol[m];                     \
    trowB[m] = row * 2048u; outix[m] = row;                                   \
  }                                                                           \
  if (bal) {                                                                  \
    unsigned cntp = (unsigned)__popcll(bal);                                  \
    int ldr = (int)__ffsll(bal) - 1;                                          \
    unsigned basep = 0;                                                       \
    if ((tid & 63) == ldr) basep = atomicAdd(ctr, cntp);                      \
    basep = __shfl(basep, ldr);                                               \
    if (need) {                                                               \
      unsigned idx = basep +                                                  \
          (unsigned)__popcll(bal & ((1ull << (tid & 63)) - 1ull));            \
      if (idx < nseg) {                                                       \
        uint2 sg = flat[idx];                                                 \
        int t0s = (int)(sg.x & 0xFFFFu); int bb = (int)(sg.x >> 16);          \
        tcur[m] = t0s; tend[m] = (int)sg.y; bcol[m] = bb; keepm[m] = 0.f;     \
        unsigned row = (unsigned)t0s * 32u + (unsigned)bb;                    \
        trowB[m] = row * 2048u; outix[m] = row;                               \
        h8 zz = {0,0,0,0,0,0,0,0};                                            \
        _Pragma("unroll") for (int i2 = 0; i2 < 33; ++i2)                     \
          *(h8*)(Hbuf + (size_t)m * HSTR + i2 * 8) = zz;                      \
      } else {                                                                \
        alivef[m] = 0; outix[m] = 0xFFFFFFFFu; trowB[m] = 0;                  \
        keepm[m] = 0.f;                                                       \
      }                                                                       \
    }                                                                         \
  }                                                                           \
} while (0)

__global__ __launch_bounds__(1024) void lstm_scan_mfma(
    const _Float16* __restrict__ xw,
    const _Float16* __restrict__ wpack,
    const float* __restrict__ Wproj,
    const float* __restrict__ bproj,
    const uint2* __restrict__ flat,
    unsigned* __restrict__ meta,
    float* __restrict__ out) {
  __shared__ __align__(16) _Float16 Wlds[64 * 64 * 8];      // 64 KB (ks 2)
  __shared__ __align__(16) _Float16 xwlds[32 * XSTR];       // 66.3 KB
  __shared__ __align__(16) _Float16 Hbuf[32 * HSTR];        // 16.9 KB
  __shared__ __align__(16) float pbuf[16][32];              // 2 KB
  __shared__ __align__(16) unsigned trowB[32];
  __shared__ __align__(16) float keepm[32];
  __shared__ unsigned outix[32];
  __shared__ int tcur[32], tend[32], bcol[32], alivef[32];

  const int tid = threadIdx.x;
  const int l = tid & 63;
  const int w = tid >> 6;        // wave 0..15
  const int q = l >> 4;
  const int r16 = l & 15;
  const int hh = 16 * w + r16;   // this lane's hidden column
  const char* xwc = (const char*)xw;
  unsigned* ctr = meta;
  const unsigned nseg = meta[1];

  // init: LDS weights (kstep 2), zero Hbuf
  for (int it = 0; it < 4; ++it) {
    int idx = it * 1024 + tid;   // 4096 h8 frags: nt*64 + ll
    int nt = idx >> 6;
    int ll = idx & 63;
    *(h8*)(Wlds + (size_t)idx * 8) =
        *(const h8*)(wpack + (((size_t)(nt * 8 + 2)) * 64 + ll) * 8);
  }
  for (int i = tid; i < 32 * HSTR / 8; i += 1024) {
    h8 z = {0,0,0,0,0,0,0,0};
    *(h8*)(Hbuf + (size_t)i * 8) = z;
  }
  // register weights: ksteps 0..1, 4 n-tiles of this wave (32 VGPR)
  h8 wr[4][2];
#pragma unroll
  for (int g = 0; g < 4; ++g)
#pragma unroll
    for (int ks = 0; ks < 2; ++ks)
      wr[g][ks] = *WPK16(g, ks);

  const float wpv = Wproj[hh];
  const float bp = bproj[0];
  if (tid < 32) {
    alivef[tid] = 1; tcur[tid] = 0; tend[tid] = 0; bcol[tid] = 0;
    outix[tid] = 0xFFFFFFFFu; trowB[tid] = 0; keepm[tid] = 0.f;
  }
  float cst[8] = {0, 0, 0, 0, 0, 0, 0, 0};
  __syncthreads();
  if (tid < 32) CONTROL_STEP;  // initial segment pulls
  int nalive = __syncthreads_count(tid < 32 ? alivef[tid] : 0);

  while (nalive > 0) {
    // --- issue xw staging for THIS step (drains at B0's vmcnt(0)) ---
    // 64 chunks of 1 KB (half-rows); wave w stages chunk c = rnd*16 + w.
#pragma unroll
    for (int rnd = 0; rnd < 4; ++rnd) {
      int c = rnd * 16 + w;
      unsigned rowB = trowB[c >> 1];
      const char* src = xwc + (size_t)rowB + (size_t)((c & 1) * 1024) + (size_t)l * 16;
      _Float16* dst = xwlds + (size_t)(c >> 1) * XSTR + (c & 1) * 512;
      __builtin_amdgcn_global_load_lds((const uint32_t*)src, (uint32_t*)dst, 16, 0, 0);
    }

    f4 z4 = {0.f, 0.f, 0.f, 0.f};
    f4 acc[2][4];
#pragma unroll
    for (int mt = 0; mt < 2; ++mt)
#pragma unroll
      for (int g = 0; g < 4; ++g) acc[mt][g] = z4;
    h8 sA[4], sB[4];

    // stream schedule: each buffer consumed >=16 MFMA after its issue
    LOAD_S(sA, 3); LOAD_S(sB, 4);
    MFK_REG(0);
    MFK_REG(1);
    MFK_W2();
    MFK_S(sA, 3); LOAD_S(sA, 5);
    MFK_S(sB, 4); LOAD_S(sB, 6);
    MFK_S(sA, 5); LOAD_S(sA, 7);
    MFK_S(sB, 6);
    MFK_S(sA, 7);

    __syncthreads();  // B0: Hbuf reads done; xw staging drained

    // xw add from LDS
    XRD(0, 0); XRD(0, 1); XRD(0, 2); XRD(0, 3);
    XRD(1, 0); XRD(1, 1); XRD(1, 2); XRD(1, 3);

    // nonlinearity + state update + h-write + projection partial (wave-local)
    f4 kp0 = *(const f4*)&keepm[q * 4];
    f4 kp1 = *(const f4*)&keepm[16 + q * 4];
    float pr[8];
#pragma unroll
    for (int r = 0; r < 4; ++r) {
      float gi = sigmf(acc[0][0][r]);
      float gf = sigmf(acc[0][1][r]);
      float gg = tanhf_(acc[0][2][r]);
      float go = sigmf(acc[0][3][r]);
      float cn = gf * (cst[r] * kp0[r]) + gi * gg;
      cst[r] = cn;
      float hv = go * tanhf_(cn);
      Hbuf[(q * 4 + r) * HSTR + hh] = (_Float16)hv;
      pr[r] = hv * wpv;
    }
#pragma unroll
    for (int r = 0; r < 4; ++r) {
      float gi = sigmf(acc[1][0][r]);
      float gf = sigmf(acc[1][1][r]);
      float gg = tanhf_(acc[1][2][r]);
      float go = sigmf(acc[1][3][r]);
      float cn = gf * (cst[4 + r] * kp1[r]) + gi * gg;
      cst[4 + r] = cn;
      float hv = go * tanhf_(cn);
      Hbuf[(16 + q * 4 + r) * HSTR + hh] = (_Float16)hv;
      pr[4 + r] = hv * wpv;
    }
    // reduce projection over the 16 hh-lanes (bits 0..3 of lane id)
#pragma unroll
    for (int jj = 0; jj < 8; ++jj) {
      pr[jj] += __shfl_xor(pr[jj], 1);
      pr[jj] += __shfl_xor(pr[jj], 2);
      pr[jj] += __shfl_xor(pr[jj], 4);
      pr[jj] += __shfl_xor(pr[jj], 8);
    }
    if (r16 == 0) {
#pragma unroll
      for (int jj = 0; jj < 8; ++jj)
        pbuf[w][16 * (jj >> 2) + q * 4 + (jj & 3)] = pr[jj];
    }

    __syncthreads();  // B1: pbuf/Hbuf writes complete before control reads/zeroes
    if (tid < 32) CONTROL_STEP;
    nalive = __syncthreads_count(tid < 32 ? alivef[tid] : 0);
  }
}

// ---------------------------------------------------------------------------
extern "C" void kernel_launch(void* const* d_in, const int* in_sizes, int n_in,
                              void* d_out, int out_size, void* d_ws, size_t ws_size,
                              hipStream_t stream) {
  const float* x = (const float*)d_in[0];
  const int* reset = (const int*)d_in[1];
  const float* Wih = (const float*)d_in[2];
  const float* Whh = (const float*)d_in[3];
  const float* bih = (const float*)d_in[4];
  const float* bhh = (const float*)d_in[5];
  const float* Wproj = (const float*)d_in[6];
  const float* bproj = (const float*)d_in[7];
  float* out = (float*)d_out;

  char* ws = (char*)d_ws;
  _Float16* xw = (_Float16*)ws;                           // 268435456 B
  unsigned* starts = (unsigned*)(ws + 268435456ULL);      // 524288 B
  unsigned* segcnt = (unsigned*)(ws + 268959744ULL);      // 128 B
  uint2* flat = (uint2*)(ws + 268959872ULL);              // 1048576 B
  _Float16* wpack = (_Float16*)(ws + 270008448ULL);       // 524288 B
  unsigned* meta = (unsigned*)(ws + 270532736ULL);        // 8 B
  // extended region (guarded by ws_size):
  _Float16* xh = (_Float16*)(ws + 270532864ULL);          // 134217728 B
  _Float16* whp = (_Float16*)(ws + 404750592ULL);         // 1048576 B
  const bool big = ws_size >= 405799168ULL;
  // scratch aliased into xw region (consumed before xw is written):
  uint2* flat2 = (uint2*)ws;                              // 1048576 B

  hipLaunchKernelGGL(seg_build_kernel, dim3(32), dim3(256), 0, stream,
                     reset, starts, segcnt);
  hipLaunchKernelGGL(seg_flat_kernel, dim3(32), dim3(256), 0, stream,
                     starts, segcnt, flat2, meta);
  hipLaunchKernelGGL(seg_sort_kernel, dim3(1), dim3(1024), 0, stream,
                     flat2, flat, meta);
  hipLaunchKernelGGL(wpack_kernel, dim3(128), dim3(256), 0, stream,
                     Whh, wpack);
  if (big) {
    hipLaunchKernelGGL(xcvt_kernel, dim3(2048), dim3(256), 0, stream, x, xh);
    hipLaunchKernelGGL(whcvt_kernel, dim3(256), dim3(256), 0, stream,
                       Wih, whp);
    hipLaunchKernelGGL(xw_gemm_f16, dim3(8192), dim3(256), 0, stream,
                       xh, whp, bih, bhh, xw);
  } else {
    hipLaunchKernelGGL(xw_gemm_kernel, dim3(8192), dim3(256), 0, stream,
                       x, Wih, bih, bhh, xw);
  }
  hipLaunchKernelGGL(lstm_scan_mfma, dim3(256), dim3(1024), 0, stream,
                     xw, wpack, Wproj, bproj, flat, meta, out);
}